// Round 6
// baseline (4517.625 us; speedup 1.0000x reference)
//
#include <hip/hip_runtime.h>
#include <stdint.h>
#include <stddef.h>

// Reverse LSTM: T=256, B=64, D=H=1024.
// Phase 0: cast x, W_ih to bf16; h0 -> tagged u32.
// Phase 1: P[t][n][b] = bf16( x[t,b,:]@W_ih[n,:] + b_ih[n] + b_hh[n] )  (bf16 MFMA GEMM)
// Phase 2: persistent kernel, 64 WGs; per-step gates = P + h@W_hh_sliceT.
//   BARRIER-FREE cross-XCD handoff: h stored as self-validating tagged words
//   u32 = (bf16<<16) | (step-tag), via sc0 sc1 write-through (MALL). Readers
//   load tagged words (sc0 sc1), validate tag in registers, retry stale lanes.
//   No flags, no drains, no fences. 4-deep rotating buffer (skew < 1 step).
//   Tag buffers memset per launch (tags repeat across graph replays).

typedef unsigned short u16;
typedef __attribute__((ext_vector_type(4))) unsigned short u16x4;
typedef __attribute__((ext_vector_type(8))) short short8;
typedef __attribute__((ext_vector_type(4))) float f32x4;
typedef __attribute__((ext_vector_type(4))) unsigned int u32x4;

#define T_LEN 256
#define YS_ELEMS (256 * 64 * 1024)  // 16777216

__device__ __forceinline__ u16 f2bf(float f) {
  union { float f; unsigned int i; } v; v.f = f;
  unsigned int r = v.i + 0x7FFFu + ((v.i >> 16) & 1u);  // RNE
  return (u16)(r >> 16);
}
__device__ __forceinline__ float bf2f(u16 u) {
  union { unsigned int i; float f; } v; v.i = ((unsigned int)u) << 16; return v.f;
}
__device__ __forceinline__ void gload_lds16(const void* g, void* l) {
  __builtin_amdgcn_global_load_lds(
      (const __attribute__((address_space(1))) unsigned int*)g,
      (__attribute__((address_space(3))) unsigned int*)l, 16, 0, 0);
}
__device__ __forceinline__ float sigm_fast(float x) { return 1.f / (1.f + __expf(-x)); }

// device-coherent 16B load with compile-time byte offset (no wait; counted vmcnt)
// NOTE gfx950 asm modifier order: offset: BEFORE sc0 sc1
#define ISSUE_LD16_OFF(dst, ptr, off)                                   \
  asm volatile("global_load_dwordx4 %0, %1, off offset:%c2 sc0 sc1"     \
               : "=v"(dst) : "v"(ptr), "i"(off) : "memory")

// plain cached 8B load, ordered among our asm VMEM ops
#define LD8_PLAIN(dst, ptr)                                             \
  asm volatile("global_load_dwordx2 %0, %1, off"                        \
               : "=v"(dst) : "v"(ptr) : "memory")

// device-coherent 4B write-through store (to MALL)
#define ST_DWORD_WT(ptr, val)                                           \
  asm volatile("global_store_dword %0, %1, off sc0 sc1"                 \
               :: "v"(ptr), "v"(val) : "memory")

#define WAIT_VM16() do { asm volatile("s_waitcnt vmcnt(16)" ::: "memory"); \
                         __builtin_amdgcn_sched_barrier(0); } while (0)
#define WAIT_VM0()  do { asm volatile("s_waitcnt vmcnt(0)"  ::: "memory"); \
                         __builtin_amdgcn_sched_barrier(0); } while (0)

__device__ __forceinline__ unsigned vpair(const u32x4 a, const u32x4 b, unsigned tag) {
  return ((a.x ^ tag) | (a.y ^ tag) | (a.z ^ tag) | (a.w ^ tag) |
          (b.x ^ tag) | (b.y ^ tag) | (b.z ^ tag) | (b.w ^ tag)) & 0xFFFFu;
}
__device__ __forceinline__ short8 strip8(const u32x4 a, const u32x4 b) {
  union { unsigned u[4]; short8 s; } r;
  r.u[0] = (a.x >> 16) | (a.y & 0xFFFF0000u);
  r.u[1] = (a.z >> 16) | (a.w & 0xFFFF0000u);
  r.u[2] = (b.x >> 16) | (b.y & 0xFFFF0000u);
  r.u[3] = (b.z >> 16) | (b.w & 0xFFFF0000u);
  return r.s;
}

// ---------------- Phase 0: f32 -> bf16 cast ----------------
__global__ void cast_f32_bf16(const float* __restrict__ src, u16* __restrict__ dst, int n4) {
  int i = blockIdx.x * blockDim.x + threadIdx.x;
  const int stride = gridDim.x * blockDim.x;
  for (; i < n4; i += stride) {
    float4 v = ((const float4*)src)[i];
    u16x4 o;
    o[0] = f2bf(v.x); o[1] = f2bf(v.y); o[2] = f2bf(v.z); o[3] = f2bf(v.w);
    ((u16x4*)dst)[i] = o;
  }
}

// h0 -> tagged u32 (tag=1) into tbuf[0]
__global__ void cast_h0_tag(const float* __restrict__ src, unsigned* __restrict__ dst) {
  int i = blockIdx.x * blockDim.x + threadIdx.x;  // 16384 threads x 4 elems
  float4 v = ((const float4*)src)[i];
  u32x4 o;
  o.x = ((unsigned)f2bf(v.x) << 16) | 1u;
  o.y = ((unsigned)f2bf(v.y) << 16) | 1u;
  o.z = ((unsigned)f2bf(v.z) << 16) | 1u;
  o.w = ((unsigned)f2bf(v.w) << 16) | 1u;
  ((u32x4*)dst)[i] = o;
}

// ---------------- Phase 1: pregate GEMM ----------------
// C[M=16384][N=4096] = X[M][1024] * Wih[N][1024]^T + bias, stored as P[t][n][b] bf16.
__global__ __launch_bounds__(256, 2) void gemm_pre(
    const u16* __restrict__ X, const u16* __restrict__ Wih,
    const float* __restrict__ bih, const float* __restrict__ bhh,
    u16* __restrict__ Pout)
{
  __shared__ u16 As[128 * 64];
  __shared__ u16 Bs[128 * 64];
  const int tid = threadIdx.x;
  const int lane = tid & 63;
  const int wid = tid >> 6;
  const int wm = wid & 1, wn = wid >> 1;
  const int Mt = blockIdx.x, Nt = blockIdx.y;

  f32x4 acc[4][4] = {};

  const int rsub = lane >> 3;                 // 0..7 (row within 8-row chunk)
  const int src_chunk = (lane & 7) ^ rsub;    // pre-swizzled 16B-chunk of the source

  for (int it = 0; it < 16; ++it) {
    const int k0 = it * 64;
    #pragma unroll
    for (int q = 0; q < 4; ++q) {
      const int j = wid * 4 + q;              // 0..15, 8 rows per instr
      const int row_local = j * 8 + rsub;     // 0..127
      const u16* ga = X   + ((size_t)(Mt * 128 + row_local)) * 1024 + k0 + src_chunk * 8;
      const u16* gb = Wih + ((size_t)(Nt * 128 + row_local)) * 1024 + k0 + src_chunk * 8;
      gload_lds16(ga, (char*)As + j * 1024);
      gload_lds16(gb, (char*)Bs + j * 1024);
    }
    __syncthreads();
    #pragma unroll
    for (int ks = 0; ks < 2; ++ks) {
      short8 af[4], bfv[4];
      #pragma unroll
      for (int f = 0; f < 4; ++f) {
        const int ra = wm * 64 + f * 16 + (lane & 15);
        const int rb = wn * 64 + f * 16 + (lane & 15);
        const int kc = ks * 4 + (lane >> 4);  // 16B chunk index within 128B row
        af[f]  = *(const short8*)((const char*)As + ra * 128 + ((kc ^ (ra & 7)) << 4));
        bfv[f] = *(const short8*)((const char*)Bs + rb * 128 + ((kc ^ (rb & 7)) << 4));
      }
      #pragma unroll
      for (int fm = 0; fm < 4; ++fm)
        #pragma unroll
        for (int fn = 0; fn < 4; ++fn)
          acc[fm][fn] = __builtin_amdgcn_mfma_f32_16x16x32_bf16(af[fm], bfv[fn], acc[fm][fn], 0, 0, 0);
    }
    __syncthreads();
  }

  const int t_out = Mt * 2 + wm;
  #pragma unroll
  for (int fn = 0; fn < 4; ++fn) {
    const int n = Nt * 128 + wn * 64 + fn * 16 + (lane & 15);
    const float bias = bih[n] + bhh[n];
    #pragma unroll
    for (int fm = 0; fm < 4; ++fm) {
      const int b = fm * 16 + ((lane >> 4) << 2);
      u16x4 o;
      #pragma unroll
      for (int r = 0; r < 4; ++r) o[r] = f2bf(acc[fm][fn][r] + bias);
      *(u16x4*)(Pout + ((size_t)t_out * 4096 + n) * 64 + b) = o;
    }
  }
}

// ---------------- Phase 2: persistent recurrence (barrier-free) ----------------
// 64 WGs x 256 threads. WG w owns hidden units [16w, 16w+16) (=> 64 gate rows).
// Static LDS = 131072 + 16384 = 147456 B exactly (launchable per R1).
__global__ __launch_bounds__(256, 1) void lstm_rec(
    const u16* __restrict__ P, const float* __restrict__ c0,
    const float* __restrict__ Whh, unsigned* __restrict__ tbuf,
    float* __restrict__ out)
{
  __shared__ u16 Ws[64 * 1024];   // slice row s = g*16+u -> W_hh[g*1024 + 16w + u][:]
  __shared__ float GX[4096];      // [g][u][b] f32, swizzled

  const int tid = threadIdx.x;
  const int lane = tid & 63;
  const int wid = tid >> 6;
  const int wg = blockIdx.x;  // 0..63

  // ---- one-time: stage W_hh slice into LDS (bf16, XOR-swizzled rows) ----
  {
    const int rowp = tid >> 2;   // slice row 0..63
    const int q = tid & 3;       // k-quarter
    const int grow = (rowp >> 4) * 1024 + wg * 16 + (rowp & 15);
    const float4* src = (const float4*)(Whh + (size_t)grow * 1024 + q * 256);
    #pragma unroll 2
    for (int j = 0; j < 32; ++j) {
      float4 v0 = src[j * 2];
      float4 v1 = src[j * 2 + 1];
      short8 pk;
      pk[0] = (short)f2bf(v0.x); pk[1] = (short)f2bf(v0.y);
      pk[2] = (short)f2bf(v0.z); pk[3] = (short)f2bf(v0.w);
      pk[4] = (short)f2bf(v1.x); pk[5] = (short)f2bf(v1.y);
      pk[6] = (short)f2bf(v1.z); pk[7] = (short)f2bf(v1.w);
      const int kc = q * 32 + j;  // 8-elem chunk index 0..127
      *(short8*)((char*)Ws + rowp * 2048 + ((kc ^ (rowp & 7)) << 4)) = pk;
    }
  }

  // pointwise role: unit u, batches b0..b0+3
  const int u = tid & 15;
  const int b0 = (tid >> 4) << 2;
  const int jh = wg * 16 + u;
  float cs[4];
  #pragma unroll
  for (int r = 0; r < 4; ++r) cs[r] = c0[(size_t)(b0 + r) * 1024 + jh];

  const int wm = wid & 1;   // batch half (rows 32*wm..+32)
  const int wn = wid >> 1;  // gate pair (slice cols 32*wn..+32)

  __syncthreads();

  // chunk issue: chunk c covers cols c*128..c*128+127 (4 MFMA K-slices)
  #define ISSUE_CH(buf, c)                                                   \
    { _Pragma("unroll")                                                      \
      for (int kq_ = 0; kq_ < 4; ++kq_) {                                    \
        ISSUE_LD16_OFF(buf[kq_][0][0], pA0, (c) * 512 + kq_ * 128);          \
        ISSUE_LD16_OFF(buf[kq_][0][1], pA0, (c) * 512 + kq_ * 128 + 16);     \
        ISSUE_LD16_OFF(buf[kq_][1][0], pA1, (c) * 512 + kq_ * 128);          \
        ISSUE_LD16_OFF(buf[kq_][1][1], pA1, (c) * 512 + kq_ * 128 + 16);     \
      } }

  #define VCHUNK(buf, badv)                                                  \
    { badv = 0;                                                              \
      _Pragma("unroll")                                                      \
      for (int kq_ = 0; kq_ < 4; ++kq_) {                                    \
        badv |= vpair(buf[kq_][0][0], buf[kq_][0][1], tag_r);                \
        badv |= vpair(buf[kq_][1][0], buf[kq_][1][1], tag_r);                \
      } }

  #define MFMACH(buf, c)                                                     \
    { _Pragma("unroll")                                                      \
      for (int kq_ = 0; kq_ < 4; ++kq_) {                                    \
        const int kabs_ = (c) * 4 + kq_;                                     \
        const short8 a0_ = strip8(buf[kq_][0][0], buf[kq_][0][1]);           \
        const short8 a1_ = strip8(buf[kq_][1][0], buf[kq_][1][1]);           \
        _Pragma("unroll")                                                    \
        for (int ni_ = 0; ni_ < 2; ++ni_) {                                  \
          const int rs_ = wn * 32 + ni_ * 16 + (lane & 15);                  \
          const int kcl_ = kabs_ * 4 + (lane >> 4);                          \
          const short8 bfr_ = *(const short8*)((const char*)Ws + rs_ * 2048  \
                              + ((kcl_ ^ (rs_ & 7)) << 4));                  \
          acc[0][ni_] = __builtin_amdgcn_mfma_f32_16x16x32_bf16(a0_, bfr_, acc[0][ni_], 0, 0, 0); \
          acc[1][ni_] = __builtin_amdgcn_mfma_f32_16x16x32_bf16(a1_, bfr_, acc[1][ni_], 0, 0, 0); \
        } } }

  for (int si = 0; si < 256; ++si) {
    const int t = 255 - si;
    const unsigned tag_r = (unsigned)(si + 1);
    const unsigned tag_w = (unsigned)(si + 2);
    const unsigned* rb  = tbuf + (size_t)(si & 3) * 65536;
    unsigned*       wbp = tbuf + (size_t)((si + 1) & 3) * 65536;

    const unsigned* pA0 = rb + (size_t)(wm * 32 +  0 + (lane & 15)) * 1024 + ((lane >> 4) << 3);
    const unsigned* pA1 = rb + (size_t)(wm * 32 + 16 + (lane & 15)) * 1024 + ((lane >> 4) << 3);

    // P loads first (oldest in vmcnt order; consumed after WAIT_VM0 at chunk 7)
    const size_t pbase = (size_t)t * 4096 * 64;
    unsigned long long Pi, Pf, Pg, Po;
    LD8_PLAIN(Pi, P + pbase + (size_t)(0 * 1024 + jh) * 64 + b0);
    LD8_PLAIN(Pf, P + pbase + (size_t)(1 * 1024 + jh) * 64 + b0);
    LD8_PLAIN(Pg, P + pbase + (size_t)(2 * 1024 + jh) * 64 + b0);
    LD8_PLAIN(Po, P + pbase + (size_t)(3 * 1024 + jh) * 64 + b0);

    f32x4 acc[2][2] = {};
    u32x4 rawA[4][2][2], rawB[4][2][2];

    ISSUE_CH(rawA, 0);
    #pragma unroll
    for (int c = 0; c < 8; ++c) {
      if ((c & 1) == 0) { if (c < 7) ISSUE_CH(rawB, c + 1); }
      else              { if (c < 7) ISSUE_CH(rawA, c + 1); }
      if (c < 7) { WAIT_VM16(); } else { WAIT_VM0(); }
      unsigned bad;
      if ((c & 1) == 0) { VCHUNK(rawA, bad); } else { VCHUNK(rawB, bad); }
      while (bad) {
        __builtin_amdgcn_s_sleep(1);
        if ((c & 1) == 0) { ISSUE_CH(rawA, c); } else { ISSUE_CH(rawB, c); }
        WAIT_VM0();
        if ((c & 1) == 0) { VCHUNK(rawA, bad); } else { VCHUNK(rawB, bad); }
      }
      if ((c & 1) == 0) { MFMACH(rawA, c); } else { MFMACH(rawB, c); }
    }

    // exchange gates through LDS (swizzled f32x4 writes)
    #pragma unroll
    for (int mi = 0; mi < 2; ++mi)
      #pragma unroll
      for (int ni = 0; ni < 2; ++ni) {
        const int g = wn * 2 + ni;
        const int uu = lane & 15;
        const int bb = wm * 32 + mi * 16 + ((lane >> 4) << 2);
        *(f32x4*)((char*)GX + ((((g * 16 + uu) * 64 + bb) << 2) ^ ((uu & 7) << 4))) = acc[mi][ni];
      }
    __syncthreads();

    const f32x4 vi = *(const f32x4*)((char*)GX + ((((0 * 16 + u) * 64 + b0) << 2) ^ ((u & 7) << 4)));
    const f32x4 vf = *(const f32x4*)((char*)GX + ((((1 * 16 + u) * 64 + b0) << 2) ^ ((u & 7) << 4)));
    const f32x4 vg = *(const f32x4*)((char*)GX + ((((2 * 16 + u) * 64 + b0) << 2) ^ ((u & 7) << 4)));
    const f32x4 vo = *(const f32x4*)((char*)GX + ((((3 * 16 + u) * 64 + b0) << 2) ^ ((u & 7) << 4)));

    #pragma unroll
    for (int r = 0; r < 4; ++r) {
      const float xi = vi[r] + bf2f((u16)(Pi >> (16 * r)));
      const float xf = vf[r] + bf2f((u16)(Pf >> (16 * r)));
      const float xg = vg[r] + bf2f((u16)(Pg >> (16 * r)));
      const float xo = vo[r] + bf2f((u16)(Po >> (16 * r)));
      const float ig = sigm_fast(xi);
      const float fg = sigm_fast(xf);
      const float og = sigm_fast(xo);
      const float cn = fg * cs[r] + ig * tanhf(xg);
      const float hv = og * tanhf(cn);
      cs[r] = cn;
      out[((size_t)t * 64 + b0 + r) * 1024 + jh] = hv;   // ys (plain cached store)
      if (si < 255) {
        // self-validating h push: (bf16 << 16) | tag, write-through to MALL
        const unsigned hb = ((unsigned)f2bf(hv) << 16) | tag_w;
        ST_DWORD_WT(wbp + (size_t)(b0 + r) * 1024 + jh, hb);
      } else {
        out[YS_ELEMS + (size_t)(b0 + r) * 1024 + jh] = hv;          // hT
        out[YS_ELEMS + 65536 + (size_t)(b0 + r) * 1024 + jh] = cn;  // cT
      }
    }

    __syncthreads();  // GX reuse guard for next step
  }
  #undef ISSUE_CH
  #undef VCHUNK
  #undef MFMACH
}

// ---------------- launch ----------------
extern "C" void kernel_launch(void* const* d_in, const int* in_sizes, int n_in,
                              void* d_out, int out_size, void* d_ws, size_t ws_size,
                              hipStream_t stream) {
  const float* x   = (const float*)d_in[0];
  const float* h0  = (const float*)d_in[1];
  const float* c0  = (const float*)d_in[2];
  const float* Wih = (const float*)d_in[3];
  const float* Whh = (const float*)d_in[4];
  const float* bih = (const float*)d_in[5];
  const float* bhh = (const float*)d_in[6];
  float* out = (float*)d_out;

  char* ws = (char*)d_ws;
  u16* x_bf      = (u16*)(ws + 0);           // 33,554,432 B (first 1MB reused as tbuf later)
  unsigned* tbuf = (unsigned*)(ws + 0);      //  1,048,576 B (4 x 256KB tagged h buffers)
  u16* wih_bf    = (u16*)(ws + 33554432);    //  8,388,608 B
  u16* Pp        = (u16*)(ws + 41943040);    // 134,217,728 B

  hipLaunchKernelGGL(cast_f32_bf16, dim3(2048), dim3(256), 0, stream, x,   x_bf,   4194304);
  hipLaunchKernelGGL(cast_f32_bf16, dim3(1024), dim3(256), 0, stream, Wih, wih_bf, 1048576);
  hipLaunchKernelGGL(gemm_pre, dim3(128, 32), dim3(256), 0, stream, x_bf, wih_bf, bih, bhh, Pp);
  // x_bf dead after gemm_pre: recycle its first 1MB as the tagged h ring
  hipMemsetAsync(tbuf, 0, 1 << 20, stream);
  hipLaunchKernelGGL(cast_h0_tag, dim3(64), dim3(256), 0, stream, h0, tbuf);

  const u16* Pc = Pp;
  void* kargs[5];
  kargs[0] = (void*)&Pc;
  kargs[1] = (void*)&c0;
  kargs[2] = (void*)&Whh;
  kargs[3] = (void*)&tbuf;
  kargs[4] = (void*)&out;
  hipLaunchCooperativeKernel((void*)lstm_rec, dim3(64), dim3(256), kargs, 0, stream);
}

// Round 7
// 3011.366 us; speedup vs baseline: 1.5002x; 1.5002x over previous
//
#include <hip/hip_runtime.h>
#include <stdint.h>
#include <stddef.h>

// Reverse LSTM: T=256, B=64, D=H=1024.
// Phase 0: cast x, W_ih to bf16; h0 -> ring[0].
// Phase 1: P[t][n][b] = bf16( x[t,b,:]@W_ih[n,:] + b_ih[n] + b_hh[n] )  (bf16 MFMA GEMM)
// Phase 2: persistent cooperative kernel, 64 WGs; per-step gates = P + h@W_hh_sliceT.
//   h handoff: 256 DISTINCT per-step buffers (ring, 32MB, recycled x_bf region).
//   Writers publish via coalesced 8B write-through (sc0 sc1) stores -> MALL home,
//   no dirty L2 lines anywhere. Readers use PLAIN CACHED loads: each 128B line is
//   fetched once per XCD from MALL, then L2/L1 serve the all-gather (requests/step
//   drop ~100x vs uncached). Safe because each buffer is written exactly once per
//   run before its first (flag-ordered) read; cross-replay L2 hits are value-
//   identical (deterministic). Flag barrier: 1 flag per 128B line (parallel MALL
//   fan-in), atomicAdd publish, relaxed-agent poll (R4-proven).

typedef unsigned short u16;
typedef __attribute__((ext_vector_type(4))) unsigned short u16x4;
typedef __attribute__((ext_vector_type(8))) short short8;
typedef __attribute__((ext_vector_type(4))) float f32x4;

#define T_LEN 256
#define YS_ELEMS (256 * 64 * 1024)  // 16777216

__device__ __forceinline__ u16 f2bf(float f) {
  union { float f; unsigned int i; } v; v.f = f;
  unsigned int r = v.i + 0x7FFFu + ((v.i >> 16) & 1u);  // RNE
  return (u16)(r >> 16);
}
__device__ __forceinline__ float bf2f(u16 u) {
  union { unsigned int i; float f; } v; v.i = ((unsigned int)u) << 16; return v.f;
}
__device__ __forceinline__ void gload_lds16(const void* g, void* l) {
  __builtin_amdgcn_global_load_lds(
      (const __attribute__((address_space(1))) unsigned int*)g,
      (__attribute__((address_space(3))) unsigned int*)l, 16, 0, 0);
}
__device__ __forceinline__ float sigm_fast(float x) { return 1.f / (1.f + __expf(-x)); }

// plain CACHED 16B load with compile-time byte offset (no wait; counted vmcnt)
#define ISSUE_LD16C(dst, ptr, off)                                      \
  asm volatile("global_load_dwordx4 %0, %1, off offset:%c2"             \
               : "=v"(dst) : "v"(ptr), "i"(off) : "memory")

// plain cached 8B load, ordered among our asm VMEM ops
#define LD8_PLAIN(dst, ptr)                                             \
  asm volatile("global_load_dwordx2 %0, %1, off"                        \
               : "=v"(dst) : "v"(ptr) : "memory")

// device-coherent 8B write-through store (to MALL home)
#define ST8_WT(ptr, val)                                                \
  asm volatile("global_store_dwordx2 %0, %1, off sc0 sc1"               \
               :: "v"(ptr), "v"(val) : "memory")

#define WAIT_VM16() do { asm volatile("s_waitcnt vmcnt(16)" ::: "memory"); \
                         __builtin_amdgcn_sched_barrier(0); } while (0)
#define WAIT_VM0()  do { asm volatile("s_waitcnt vmcnt(0)"  ::: "memory"); \
                         __builtin_amdgcn_sched_barrier(0); } while (0)

// ---------------- Phase 0: f32 -> bf16 cast ----------------
__global__ void cast_f32_bf16(const float* __restrict__ src, u16* __restrict__ dst, int n4) {
  int i = blockIdx.x * blockDim.x + threadIdx.x;
  const int stride = gridDim.x * blockDim.x;
  for (; i < n4; i += stride) {
    float4 v = ((const float4*)src)[i];
    u16x4 o;
    o[0] = f2bf(v.x); o[1] = f2bf(v.y); o[2] = f2bf(v.z); o[3] = f2bf(v.w);
    ((u16x4*)dst)[i] = o;
  }
}

// ---------------- Phase 1: pregate GEMM ----------------
// C[M=16384][N=4096] = X[M][1024] * Wih[N][1024]^T + bias, stored as P[t][n][b] bf16.
__global__ __launch_bounds__(256, 2) void gemm_pre(
    const u16* __restrict__ X, const u16* __restrict__ Wih,
    const float* __restrict__ bih, const float* __restrict__ bhh,
    u16* __restrict__ Pout)
{
  __shared__ u16 As[128 * 64];
  __shared__ u16 Bs[128 * 64];
  const int tid = threadIdx.x;
  const int lane = tid & 63;
  const int wid = tid >> 6;
  const int wm = wid & 1, wn = wid >> 1;
  const int Mt = blockIdx.x, Nt = blockIdx.y;

  f32x4 acc[4][4] = {};

  const int rsub = lane >> 3;                 // 0..7 (row within 8-row chunk)
  const int src_chunk = (lane & 7) ^ rsub;    // pre-swizzled 16B-chunk of the source

  for (int it = 0; it < 16; ++it) {
    const int k0 = it * 64;
    #pragma unroll
    for (int q = 0; q < 4; ++q) {
      const int j = wid * 4 + q;              // 0..15, 8 rows per instr
      const int row_local = j * 8 + rsub;     // 0..127
      const u16* ga = X   + ((size_t)(Mt * 128 + row_local)) * 1024 + k0 + src_chunk * 8;
      const u16* gb = Wih + ((size_t)(Nt * 128 + row_local)) * 1024 + k0 + src_chunk * 8;
      gload_lds16(ga, (char*)As + j * 1024);
      gload_lds16(gb, (char*)Bs + j * 1024);
    }
    __syncthreads();
    #pragma unroll
    for (int ks = 0; ks < 2; ++ks) {
      short8 af[4], bfv[4];
      #pragma unroll
      for (int f = 0; f < 4; ++f) {
        const int ra = wm * 64 + f * 16 + (lane & 15);
        const int rb = wn * 64 + f * 16 + (lane & 15);
        const int kc = ks * 4 + (lane >> 4);  // 16B chunk index within 128B row
        af[f]  = *(const short8*)((const char*)As + ra * 128 + ((kc ^ (ra & 7)) << 4));
        bfv[f] = *(const short8*)((const char*)Bs + rb * 128 + ((kc ^ (rb & 7)) << 4));
      }
      #pragma unroll
      for (int fm = 0; fm < 4; ++fm)
        #pragma unroll
        for (int fn = 0; fn < 4; ++fn)
          acc[fm][fn] = __builtin_amdgcn_mfma_f32_16x16x32_bf16(af[fm], bfv[fn], acc[fm][fn], 0, 0, 0);
    }
    __syncthreads();
  }

  const int t_out = Mt * 2 + wm;
  #pragma unroll
  for (int fn = 0; fn < 4; ++fn) {
    const int n = Nt * 128 + wn * 64 + fn * 16 + (lane & 15);
    const float bias = bih[n] + bhh[n];
    #pragma unroll
    for (int fm = 0; fm < 4; ++fm) {
      const int b = fm * 16 + ((lane >> 4) << 2);
      u16x4 o;
      #pragma unroll
      for (int r = 0; r < 4; ++r) o[r] = f2bf(acc[fm][fn][r] + bias);
      *(u16x4*)(Pout + ((size_t)t_out * 4096 + n) * 64 + b) = o;
    }
  }
}

// ---------------- Phase 2: persistent recurrence ----------------
// 64 WGs x 256 threads. WG w owns hidden units [16w, 16w+16) (=> 64 gate rows).
// Static LDS = 131072 + 16384 = 147456 B exactly (launchable per R1).
__global__ __launch_bounds__(256, 1) void lstm_rec(
    const u16* __restrict__ P, const float* __restrict__ c0,
    const float* __restrict__ Whh, u16* __restrict__ ring,
    float* __restrict__ out, int* __restrict__ flags)
{
  __shared__ u16 Ws[64 * 1024];   // slice row s = g*16+u -> W_hh[g*1024 + 16w + u][:]
  __shared__ float GX[4096];      // [g][u][b] f32, swizzled; first 2KB reused as HXu

  const int tid = threadIdx.x;
  const int lane = tid & 63;
  const int wid = tid >> 6;
  const int wg = blockIdx.x;  // 0..63

  // ---- one-time: stage W_hh slice into LDS (bf16, XOR-swizzled rows) ----
  {
    const int rowp = tid >> 2;   // slice row 0..63
    const int q = tid & 3;       // k-quarter
    const int grow = (rowp >> 4) * 1024 + wg * 16 + (rowp & 15);
    const float4* src = (const float4*)(Whh + (size_t)grow * 1024 + q * 256);
    #pragma unroll 2
    for (int j = 0; j < 32; ++j) {
      float4 v0 = src[j * 2];
      float4 v1 = src[j * 2 + 1];
      short8 pk;
      pk[0] = (short)f2bf(v0.x); pk[1] = (short)f2bf(v0.y);
      pk[2] = (short)f2bf(v0.z); pk[3] = (short)f2bf(v0.w);
      pk[4] = (short)f2bf(v1.x); pk[5] = (short)f2bf(v1.y);
      pk[6] = (short)f2bf(v1.z); pk[7] = (short)f2bf(v1.w);
      const int kc = q * 32 + j;  // 8-elem chunk index 0..127
      *(short8*)((char*)Ws + rowp * 2048 + ((kc ^ (rowp & 7)) << 4)) = pk;
    }
  }

  // pointwise role: unit u, batches b0..b0+3
  const int u = tid & 15;
  const int b0 = (tid >> 4) << 2;
  const int jh = wg * 16 + u;
  float cs[4];
  #pragma unroll
  for (int r = 0; r < 4; ++r) cs[r] = c0[(size_t)(b0 + r) * 1024 + jh];

  // h-publish role: row srow (batch), 8B chunk sq
  const int srow = tid >> 2;
  const int sq = tid & 3;

  const int wm = wid & 1;   // batch half (rows 32*wm..+32)
  const int wn = wid >> 1;  // gate pair (slice cols 32*wn..+32)

  u16* HXu = (u16*)GX;      // 2KB staging area aliasing GX (guarded by barriers)

  __syncthreads();

  // quarter issue (plain cached): quarter qi covers cols qi*256..+255 (8 MFMA K-slices)
  #define ISSUE_Q(buf, qi)                                                     \
    { _Pragma("unroll")                                                        \
      for (int kq_ = 0; kq_ < 8; ++kq_) {                                      \
        ISSUE_LD16C(buf[kq_][0], pA0, (qi) * 512 + kq_ * 64);                  \
        ISSUE_LD16C(buf[kq_][1], pA1, (qi) * 512 + kq_ * 64);                  \
      } }

  #define MFMA_Q(buf, qi)                                                      \
    { _Pragma("unroll")                                                        \
      for (int kq_ = 0; kq_ < 8; ++kq_) {                                      \
        const int kabs_ = (qi) * 8 + kq_;                                      \
        _Pragma("unroll")                                                      \
        for (int ni_ = 0; ni_ < 2; ++ni_) {                                    \
          const int rs_ = wn * 32 + ni_ * 16 + (lane & 15);                    \
          const int kcl_ = kabs_ * 4 + (lane >> 4);                            \
          const short8 bfr_ = *(const short8*)((const char*)Ws + rs_ * 2048    \
                              + ((kcl_ ^ (rs_ & 7)) << 4));                    \
          acc[0][ni_] = __builtin_amdgcn_mfma_f32_16x16x32_bf16(buf[kq_][0], bfr_, acc[0][ni_], 0, 0, 0); \
          acc[1][ni_] = __builtin_amdgcn_mfma_f32_16x16x32_bf16(buf[kq_][1], bfr_, acc[1][ni_], 0, 0, 0); \
        } } }

  for (int si = 0; si < 256; ++si) {
    const int t = 255 - si;
    const u16* rb = ring + (size_t)si * 65536;        // h state for this step
    u16*       wb = ring + (size_t)(si + 1) * 65536;  // next h (si<255 only)

    const u16* pA0 = rb + (size_t)(wm * 32 +  0 + (lane & 15)) * 1024 + ((lane >> 4) << 3);
    const u16* pA1 = rb + (size_t)(wm * 32 + 16 + (lane & 15)) * 1024 + ((lane >> 4) << 3);

    // P loads first (oldest in vmcnt order)
    const size_t pbase = (size_t)t * 4096 * 64;
    unsigned long long Pi, Pf, Pg, Po;
    LD8_PLAIN(Pi, P + pbase + (size_t)(0 * 1024 + jh) * 64 + b0);
    LD8_PLAIN(Pf, P + pbase + (size_t)(1 * 1024 + jh) * 64 + b0);
    LD8_PLAIN(Pg, P + pbase + (size_t)(2 * 1024 + jh) * 64 + b0);
    LD8_PLAIN(Po, P + pbase + (size_t)(3 * 1024 + jh) * 64 + b0);

    f32x4 acc[2][2] = {};
    short8 afrA[8][2], afrB[8][2];

    // 4-quarter pipelined cached h loads + MFMA
    ISSUE_Q(afrA, 0)
    ISSUE_Q(afrB, 1)
    WAIT_VM16();          // P + q0 ready
    MFMA_Q(afrA, 0)
    ISSUE_Q(afrA, 2)
    WAIT_VM16();          // q1 ready
    MFMA_Q(afrB, 1)
    ISSUE_Q(afrB, 3)
    WAIT_VM16();          // q2 ready
    MFMA_Q(afrA, 2)
    WAIT_VM0();           // q3 ready
    MFMA_Q(afrB, 3)

    // exchange gates through LDS (swizzled f32x4 writes)
    #pragma unroll
    for (int mi = 0; mi < 2; ++mi)
      #pragma unroll
      for (int ni = 0; ni < 2; ++ni) {
        const int g = wn * 2 + ni;
        const int uu = lane & 15;
        const int bb = wm * 32 + mi * 16 + ((lane >> 4) << 2);
        *(f32x4*)((char*)GX + ((((g * 16 + uu) * 64 + bb) << 2) ^ ((uu & 7) << 4))) = acc[mi][ni];
      }
    __syncthreads();

    const f32x4 vi = *(const f32x4*)((char*)GX + ((((0 * 16 + u) * 64 + b0) << 2) ^ ((u & 7) << 4)));
    const f32x4 vf = *(const f32x4*)((char*)GX + ((((1 * 16 + u) * 64 + b0) << 2) ^ ((u & 7) << 4)));
    const f32x4 vg = *(const f32x4*)((char*)GX + ((((2 * 16 + u) * 64 + b0) << 2) ^ ((u & 7) << 4)));
    const f32x4 vo = *(const f32x4*)((char*)GX + ((((3 * 16 + u) * 64 + b0) << 2) ^ ((u & 7) << 4)));

    float hvv[4];
    #pragma unroll
    for (int r = 0; r < 4; ++r) {
      const float xi = vi[r] + bf2f((u16)(Pi >> (16 * r)));
      const float xf = vf[r] + bf2f((u16)(Pf >> (16 * r)));
      const float xg = vg[r] + bf2f((u16)(Pg >> (16 * r)));
      const float xo = vo[r] + bf2f((u16)(Po >> (16 * r)));
      const float ig = sigm_fast(xi);
      const float fg = sigm_fast(xf);
      const float og = sigm_fast(xo);
      const float cn = fg * cs[r] + ig * tanhf(xg);
      const float hv = og * tanhf(cn);
      cs[r] = cn;
      hvv[r] = hv;
      out[((size_t)t * 64 + b0 + r) * 1024 + jh] = hv;   // ys (plain cached store)
      if (si == 255) {
        out[YS_ELEMS + (size_t)(b0 + r) * 1024 + jh] = hv;          // hT
        out[YS_ELEMS + 65536 + (size_t)(b0 + r) * 1024 + jh] = cn;  // cT
      }
    }

    if (si < 255) {
      __syncthreads();  // all GX gate reads done; safe to overwrite with HXu
      #pragma unroll
      for (int r = 0; r < 4; ++r) HXu[(b0 + r) * 16 + u] = f2bf(hvv[r]);
      __syncthreads();  // HXu complete
      // coalesced 8B write-through publish: straight to MALL, no dirty L2 lines
      {
        const unsigned long long hv8 = *(const unsigned long long*)(HXu + srow * 16 + sq * 4);
        ST8_WT(wb + (size_t)srow * 1024 + wg * 16 + sq * 4, hv8);
      }
      WAIT_VM0();        // h publish (and ys stores) performed
      __syncthreads();   // whole WG drained
      if (tid == 0) atomicAdd(&flags[wg << 5], 1);   // 1 flag per 128B line
      if (tid < 64) {
        while (__hip_atomic_load(&flags[tid << 5], __ATOMIC_RELAXED, __HIP_MEMORY_SCOPE_AGENT) < si + 1)
          __builtin_amdgcn_s_sleep(2);
      }
      __syncthreads();
    }
  }
  #undef ISSUE_Q
  #undef MFMA_Q
}

// ---------------- launch ----------------
extern "C" void kernel_launch(void* const* d_in, const int* in_sizes, int n_in,
                              void* d_out, int out_size, void* d_ws, size_t ws_size,
                              hipStream_t stream) {
  const float* x   = (const float*)d_in[0];
  const float* h0  = (const float*)d_in[1];
  const float* c0  = (const float*)d_in[2];
  const float* Wih = (const float*)d_in[3];
  const float* Whh = (const float*)d_in[4];
  const float* bih = (const float*)d_in[5];
  const float* bhh = (const float*)d_in[6];
  float* out = (float*)d_out;

  char* ws = (char*)d_ws;
  u16* x_bf   = (u16*)(ws + 0);           // 33,554,432 B; recycled as h ring after gemm_pre
  u16* ring   = (u16*)(ws + 0);           // 256 x 131072 B = 33,554,432 B
  u16* wih_bf = (u16*)(ws + 33554432);    //  8,388,608 B
  u16* Pp     = (u16*)(ws + 41943040);    // 134,217,728 B
  int* flags  = (int*)(ws + 176160768);   //      8,192 B (64 flags, 128B-padded)

  hipLaunchKernelGGL(cast_f32_bf16, dim3(2048), dim3(256), 0, stream, x,   x_bf,   4194304);
  hipLaunchKernelGGL(cast_f32_bf16, dim3(1024), dim3(256), 0, stream, Wih, wih_bf, 1048576);
  hipLaunchKernelGGL(gemm_pre, dim3(128, 32), dim3(256), 0, stream, x_bf, wih_bf, bih, bhh, Pp);
  // x_bf dead after gemm_pre: recycle as the per-step h ring
  hipMemsetAsync(flags, 0, 8192, stream);
  hipLaunchKernelGGL(cast_f32_bf16, dim3(64), dim3(256), 0, stream, h0, ring, 16384);

  const u16* Pc = Pp;
  void* kargs[6];
  kargs[0] = (void*)&Pc;
  kargs[1] = (void*)&c0;
  kargs[2] = (void*)&Whh;
  kargs[3] = (void*)&ring;
  kargs[4] = (void*)&out;
  kargs[5] = (void*)&flags;
  hipLaunchCooperativeKernel((void*)lstm_rec, dim3(64), dim3(256), kargs, 0, stream);
}